// Round 1
// baseline (903.841 us; speedup 1.0000x reference)
//
#include <hip/hip_runtime.h>

// Problem constants (match reference)
constexpr int N = 100000;   // nodes
constexpr int E = 2000000;  // edges per etype
constexpr int D = 256;      // in dim
constexpr int C = 16;       // out dim
constexpr int R = 4;        // etypes
constexpr int NCOL = R * C;             // 64 fused output columns
constexpr int WH_ELEMS = R * N * C;     // 6,400,000
constexpr int CNT_ELEMS = R * N;        // 400,000

// ---------------------------------------------------------------------------
// Repack W (R,D,C) -> wt2[k4][col] float4 where col = r*16+c, float4 spans
// k = 4*k4 .. 4*k4+3. Makes GEMM weight loads coalesced (1KB per wave-iter).
// ---------------------------------------------------------------------------
__global__ void wt_kernel(const float* __restrict__ W, float4* __restrict__ wt2) {
    int idx = blockIdx.x * blockDim.x + threadIdx.x;
    if (idx >= 64 * NCOL) return;      // 64 k4-chunks x 64 cols
    int k4  = idx >> 6;
    int col = idx & 63;
    int r = col >> 4, c = col & 15;
    int base = r * D * C + (k4 * 4) * C + c;
    float4 v;
    v.x = W[base];
    v.y = W[base + C];
    v.z = W[base + 2 * C];
    v.w = W[base + 3 * C];
    wt2[idx] = v;
}

// ---------------------------------------------------------------------------
// Fused per-etype linear: wh[r][n][c] = feat[n,:] @ W[r][:,c] + b[r][c]
// Block = 256 threads = 4 waves; each wave owns one row-slot, 64 lanes = 64
// fused cols. 16 rows of feat staged in LDS (stride 260 pads rows to distinct
// banks; within a wave the feat read is same-address broadcast -> free).
// ---------------------------------------------------------------------------
__global__ __launch_bounds__(256) void gemm_kernel(
    const float4* __restrict__ feat4, const float4* __restrict__ wt2,
    const float* __restrict__ b, float* __restrict__ wh) {
    __shared__ float lds[16 * 260];
    const int t  = threadIdx.x;
    const int n0 = blockIdx.x * 16;

    // Cooperative load: 16 rows x 64 float4 (N = 6250*16 exactly, no guard)
#pragma unroll
    for (int j = 0; j < 4; ++j) {
        int p = t + j * 256;
        int row = p >> 6, k4 = p & 63;
        float4 v = feat4[(n0 + row) * 64 + k4];
        float* dp = &lds[row * 260 + k4 * 4];
        dp[0] = v.x; dp[1] = v.y; dp[2] = v.z; dp[3] = v.w;
    }
    __syncthreads();

    const int col = t & 63;
    const int rowslot = t >> 6;   // == wave id: whole wave shares one row set
    const float bias = b[col];
    float acc0 = bias, acc1 = bias, acc2 = bias, acc3 = bias;

#pragma unroll 4
    for (int k4 = 0; k4 < 64; ++k4) {
        float4 w = wt2[k4 * 64 + col];   // coalesced 1KB/wave, L1-hot
        float4 f0 = *(const float4*)&lds[(rowslot     ) * 260 + k4 * 4];
        float4 f1 = *(const float4*)&lds[(rowslot +  4) * 260 + k4 * 4];
        float4 f2 = *(const float4*)&lds[(rowslot +  8) * 260 + k4 * 4];
        float4 f3 = *(const float4*)&lds[(rowslot + 12) * 260 + k4 * 4];
        acc0 += f0.x * w.x + f0.y * w.y + f0.z * w.z + f0.w * w.w;
        acc1 += f1.x * w.x + f1.y * w.y + f1.z * w.z + f1.w * w.w;
        acc2 += f2.x * w.x + f2.y * w.y + f2.z * w.z + f2.w * w.w;
        acc3 += f3.x * w.x + f3.y * w.y + f3.z * w.z + f3.w * w.w;
    }

    const int r = col >> 4, c = col & 15;
    const int base = r * N;
    wh[(base + n0 + rowslot     ) * C + c] = acc0;
    wh[(base + n0 + rowslot +  4) * C + c] = acc1;
    wh[(base + n0 + rowslot +  8) * C + c] = acc2;
    wh[(base + n0 + rowslot + 12) * C + c] = acc3;
}

// ---------------------------------------------------------------------------
// Edge scatter: 16 lanes per edge (lane = channel). Gather wh[src] (64B
// coalesced per edge group), scale by eweight, HW f32 atomics into s[dst].
// Lane 0 of each edge group bumps the in-degree counter.
// ---------------------------------------------------------------------------
__global__ void edge_kernel(const int* __restrict__ src, const int* __restrict__ dst,
                            const float* __restrict__ ew, const float* __restrict__ wh,
                            float* __restrict__ sacc, float* __restrict__ cnt) {
    const int total  = R * E * C;               // 128M lane-tasks (fits int32)
    const int stride = gridDim.x * blockDim.x;
    for (int i = blockIdx.x * blockDim.x + threadIdx.x; i < total; i += stride) {
        const int c  = i & 15;
        const int eg = i >> 4;                  // global edge id 0..R*E
        const int r  = eg / E;                  // const divide -> magic mul
        const int sn = src[eg];
        const int dn = dst[eg];
        const float w = ew[eg];
        const float m = wh[(r * N + sn) * C + c] * w;
        unsafeAtomicAdd(&sacc[(r * N + dn) * C + c], m);
        if (c == 0) unsafeAtomicAdd(&cnt[r * N + dn], 1.0f);
    }
}

// ---------------------------------------------------------------------------
// out[n][c] = sum_r (cnt_r[n] > 0 ? s_r[n][c]/cnt_r[n] : 0)
// ---------------------------------------------------------------------------
__global__ void finalize_kernel(const float* __restrict__ sacc,
                                const float* __restrict__ cnt,
                                float* __restrict__ out) {
    int idx = blockIdx.x * blockDim.x + threadIdx.x;
    if (idx >= N * C) return;
    int n = idx >> 4;
    float acc = 0.f;
#pragma unroll
    for (int r = 0; r < R; ++r) {
        float cc = cnt[r * N + n];
        float sv = sacc[r * (N * C) + idx];   // idx == n*16+c, coalesced
        if (cc > 0.f) acc += sv / cc;
    }
    out[idx] = acc;
}

extern "C" void kernel_launch(void* const* d_in, const int* in_sizes, int n_in,
                              void* d_out, int out_size, void* d_ws, size_t ws_size,
                              hipStream_t stream) {
    const float* feat = (const float*)d_in[0];
    const int*   src  = (const int*)d_in[1];
    const int*   dst  = (const int*)d_in[2];
    const float* ew   = (const float*)d_in[3];
    const float* W    = (const float*)d_in[4];
    const float* b    = (const float*)d_in[5];
    float* out = (float*)d_out;

    // Workspace layout (f32 elems): [wh 6.4M][sacc 6.4M][cnt 400K][wt2 16K]
    float* wh   = (float*)d_ws;
    float* sacc = wh + WH_ELEMS;
    float* cnt  = sacc + WH_ELEMS;
    float* wt2  = cnt + CNT_ELEMS;

    hipMemsetAsync(sacc, 0, (size_t)(WH_ELEMS + CNT_ELEMS) * sizeof(float), stream);
    wt_kernel<<<(64 * NCOL + 255) / 256, 256, 0, stream>>>(W, (float4*)wt2);
    gemm_kernel<<<N / 16, 256, 0, stream>>>((const float4*)feat, (const float4*)wt2, b, wh);
    edge_kernel<<<4096, 256, 0, stream>>>(src, dst, ew, wh, sacc, cnt);
    finalize_kernel<<<(N * C + 255) / 256, 256, 0, stream>>>(sacc, cnt, out);
}